// Round 9
// baseline (241.604 us; speedup 1.0000x reference)
//
#include <hip/hip_runtime.h>
#include <math.h>
#include <limits.h>

#define NB1 2048      // coarse bins: (float_bits >> 17) - OFF1  (64 steps/octave)
#define OFF1 6656     // = 104 << 6 : bin 0 at 2^-23; covers up to 2^9
#define NB2 4096      // fine linear histogram bins over the band
#define NREP 4        // replicated global fine-hist copies (blockIdx & 3)

// Persistent device state. Invariant: all-zero at kernel_launch entry.
// Zero-initialized at module load; final_kernel restores zeros each call
// (g_hist2, g_H1, g_bar, g_rel), so every call — including rocprof replays —
// starts from a clean state. (Cross-dispatch cleaning proven safe R4/R8.)
__device__ unsigned g_H1[NB1];
__device__ unsigned g_hist2[NREP * NB2];   // 64 KB, 4 replicated copies
__device__ float    g_band[2];
__device__ unsigned g_bar = 0;             // grid-barrier arrival counter
__device__ unsigned g_rel = 0;             // grid-barrier release flag

// loss = max(x,0) - x*t + log1p(exp(-|x|)) >= 0 ; p = sigmoid(x)
__device__ __forceinline__ void elem_f(float x, float t, float& l, float& p) {
    float e = __expf(-fabsf(x));
    l = fmaxf(x, 0.f) - x * t + __logf(1.f + e);
    float r = __builtin_amdgcn_rcpf(1.f + e);
    p = (x >= 0.f) ? r : e * r;
}

// coarse bin for a non-negative loss value (monotonic in value)
__device__ __forceinline__ int coarse_bin(float l) {
    int b = (int)(__float_as_uint(l) >> 17) - OFF1;
    return min(max(b, 0), NB1 - 1);
}

// ---------- k0: fused sample+band+main, one resident-grid kernel ----------
// Grid is chosen host-side from the occupancy API so ALL blocks are resident;
// a single hand-rolled grid barrier (atomic counter + release flag) separates
// phase A (per-block 1/16 contiguous sample -> coarse hist -> g_H1 atomics)
// from phase B (every block redundantly scans g_H1 for the band, in parallel)
// and phase C (R8's proven main loop: LDS fine-hist, NREP flush, partials).
// The __syncthreads before barrier-arrival drains this block's flush atomics
// (compiler emits vmcnt(0) before s_barrier), so the release order is sound.
__global__ __launch_bounds__(256) void fused_kernel(
    const float4* __restrict__ x4, const float4* __restrict__ t4,
    float* __restrict__ q0, float* __restrict__ q1,
    float* __restrict__ q2, float* __restrict__ q3, unsigned* __restrict__ qc,
    const float* __restrict__ xg, const float* __restrict__ tg,
    int n, int n4, int per, long long ks, long long M)
{
    __shared__ unsigned lhist[NB2];    // 16 KB: coarse hist (A/B), fine hist (C)
    __shared__ float    sband[2];
    __shared__ float    rs[4][4];
    __shared__ unsigned rc[4];

    int tid = threadIdx.x;
    long long base = (long long)blockIdx.x * per;
    int bbase = (base < n4) ? (int)base : n4;
    int bend  = min(bbase + per, n4);
    int avail = bend - bbase;

    // ---- phase A: sample first (avail>>4) float4 of this block's range ----
    for (int i = tid; i < NB1; i += 256) lhist[i] = 0u;
    __syncthreads();

    int scnt = avail >> 4;             // sampled float4 this block (1/16)
    for (int i = tid; i < scnt; i += 256) {
        float4 xa = x4[bbase + i], ta = t4[bbase + i];
        float xs[4] = {xa.x, xa.y, xa.z, xa.w};
        float ts[4] = {ta.x, ta.y, ta.z, ta.w};
        #pragma unroll
        for (int c = 0; c < 4; ++c) {
            float l, p; elem_f(xs[c], ts[c], l, p);
            atomicAdd(&lhist[coarse_bin(l)], 1u);
        }
    }
    __syncthreads();
    for (int i = tid; i < NB1; i += 256) {
        unsigned c = lhist[i];
        if (c) atomicAdd(&g_H1[i], c);
    }
    __syncthreads();                   // drains this block's atomics (vmcnt 0)

    // ---- resident-grid barrier ----
    if (tid == 0) {
        __threadfence();               // release
        unsigned a = atomicAdd(&g_bar, 1u);
        if (a == gridDim.x - 1) {
            __hip_atomic_store(&g_rel, 1u, __ATOMIC_RELEASE,
                               __HIP_MEMORY_SCOPE_AGENT);
        } else {
            while (__hip_atomic_load(&g_rel, __ATOMIC_ACQUIRE,
                                     __HIP_MEMORY_SCOPE_AGENT) == 0u)
                __builtin_amdgcn_s_sleep(8);
        }
        __threadfence();               // acquire
    }
    __syncthreads();

    // ---- phase B: every block scans the summed coarse hist (parallel) ----
    for (int i = tid; i < NB1; i += 256) lhist[i] = g_H1[i];
    __syncthreads();

    if (tid < 64) {
        int lane = tid;
        int cb = lane << 5;            // 32 bins per lane
        unsigned long long chunk = 0;
        for (int j = 0; j < 32; ++j) chunk += lhist[cb + j];
        unsigned long long s = chunk;  // inclusive suffix-scan across lanes
        #pragma unroll
        for (int off = 1; off < 64; off <<= 1) {
            unsigned long long v = __shfl_down(s, off);
            if (lane + off < 64) s += v;
        }
        unsigned long long above = s - chunk;

        int my_bhi = INT_MAX, my_blo = -1;
        unsigned long long c = above;
        for (int j = 31; j >= 0; --j) {
            unsigned h = lhist[cb + j];
            if ((long long)(c + h) < ks - M) my_bhi = cb + j;
            if ((long long)c > ks + M && my_blo < 0) my_blo = cb + j;
            c += h;
        }
        #pragma unroll
        for (int off = 32; off; off >>= 1) {
            int a = __shfl_down(my_bhi, off); my_bhi = min(my_bhi, a);
            int b = __shfl_down(my_blo, off); my_blo = max(my_blo, b);
        }
        if (lane == 0) {
            int bhi = (my_bhi == INT_MAX) ? (NB1 - 1) : my_bhi;
            int blo = my_blo;
            float vhi = __uint_as_float((unsigned)(bhi + OFF1) << 17);
            float vlo = (blo < 0) ? 0.f
                                  : __uint_as_float((unsigned)(blo + 1 + OFF1) << 17);
            if (!(vlo < vhi)) vlo = 0.f;
            sband[0] = vlo;
            sband[1] = vhi;
            if (blockIdx.x == 0) { g_band[0] = vlo; g_band[1] = vhi; }
        }
    }
    __syncthreads();
    float vlo = sband[0], vhi = sband[1];
    float scale = (float)NB2 / (vhi - vlo);

    // re-zero for the fine histogram
    for (int i = tid; i < NB2; i += 256) lhist[i] = 0u;
    __syncthreads();

    // ---- phase C: R8-proven main loop ----
    float sp = 0.f, spt = 0.f, st = 0.f, sgt = 0.f;
    unsigned cnt = 0;

    for (int idx = bbase + tid; idx < bend; idx += 256) {
        float4 xv = x4[idx], tv = t4[idx];
        float xs[4] = {xv.x, xv.y, xv.z, xv.w};
        float ts[4] = {tv.x, tv.y, tv.z, tv.w};
        #pragma unroll
        for (int c = 0; c < 4; ++c) {
            float l, p;
            elem_f(xs[c], ts[c], l, p);
            sp += p; spt += p * ts[c]; st += ts[c];
            if (l >= vhi) { cnt++; sgt += l; }
            else if (l >= vlo) {
                int b = min((int)((l - vlo) * scale), NB2 - 1);
                atomicAdd(&lhist[b], 1u);
            }
        }
    }

    // scalar tail (n % 4) on block 0
    int tail0 = n4 << 2;
    if (blockIdx.x == 0 && tid < (n - tail0)) {
        float x = xg[tail0 + tid], t = tg[tail0 + tid];
        float l, p;
        elem_f(x, t, l, p);
        sp += p; spt += p * t; st += t;
        if (l >= vhi) { cnt++; sgt += l; }
        else if (l >= vlo) {
            int b = min((int)((l - vlo) * scale), NB2 - 1);
            atomicAdd(&lhist[b], 1u);
        }
    }

    // flush private fine-hist: batched full-wave atomics, NREP-way replicated
    __syncthreads();
    {
        unsigned* dst = &g_hist2[(blockIdx.x & (NREP - 1)) * NB2];
        for (int i = tid; i < NB2; i += 256) {
            unsigned c = lhist[i];
            if (c) atomicAdd(&dst[i], c);
        }
    }

    // wave -> block reduce, then ONE private slot write per block
    #pragma unroll
    for (int off = 32; off; off >>= 1) {
        sp  += __shfl_down(sp,  off);
        spt += __shfl_down(spt, off);
        st  += __shfl_down(st,  off);
        sgt += __shfl_down(sgt, off);
        cnt += __shfl_down(cnt, off);
    }
    int w = tid >> 6;
    if ((tid & 63) == 0) {
        rs[w][0] = sp; rs[w][1] = spt; rs[w][2] = st; rs[w][3] = sgt; rc[w] = cnt;
    }
    __syncthreads();
    if (tid == 0) {
        float a0 = 0, a1 = 0, a2 = 0, a3 = 0;
        unsigned c = 0;
        #pragma unroll
        for (int i = 0; i < 4; ++i) {
            a0 += rs[i][0]; a1 += rs[i][1]; a2 += rs[i][2]; a3 += rs[i][3]; c += rc[i];
        }
        q0[blockIdx.x] = a0; q1[blockIdx.x] = a1; q2[blockIdx.x] = a2;
        q3[blockIdx.x] = a3; qc[blockIdx.x] = c;
    }
}

// ---------- k1: reduce partials + resolve threshold bin + emit ----------
// Merges NREP hist copies; self-cleans ALL persistent state for the next call
// (g_hist2, g_H1, g_bar, g_rel).
__global__ __launch_bounds__(1024) void final_kernel(
    const float* __restrict__ q0, const float* __restrict__ q1,
    const float* __restrict__ q2, const float* __restrict__ q3,
    const unsigned* __restrict__ qc, int nblocks,
    float* __restrict__ out, long long k)
{
    __shared__ unsigned lh[NB2];        // 16 KB
    __shared__ double red[16][5];
    __shared__ double fin[5];

    for (int i = threadIdx.x; i < NB2; i += 1024) {
        unsigned s = 0;
        #pragma unroll
        for (int r = 0; r < NREP; ++r) {
            s += g_hist2[r * NB2 + i];
            g_hist2[r * NB2 + i] = 0u;  // self-clean for next call
        }
        lh[i] = s;
    }
    for (int i = threadIdx.x; i < NB1; i += 1024) g_H1[i] = 0u;
    if (threadIdx.x == 0) { g_bar = 0u; g_rel = 0u; }

    double a0 = 0, a1 = 0, a2 = 0, a3 = 0, a4 = 0;
    for (int i = threadIdx.x; i < nblocks; i += 1024) {
        a0 += (double)q0[i]; a1 += (double)q1[i]; a2 += (double)q2[i];
        a3 += (double)q3[i]; a4 += (double)qc[i];
    }
    #pragma unroll
    for (int off = 32; off; off >>= 1) {
        a0 += __shfl_down(a0, off); a1 += __shfl_down(a1, off);
        a2 += __shfl_down(a2, off); a3 += __shfl_down(a3, off);
        a4 += __shfl_down(a4, off);
    }
    int w = threadIdx.x >> 6;
    if ((threadIdx.x & 63) == 0) {
        red[w][0] = a0; red[w][1] = a1; red[w][2] = a2; red[w][3] = a3; red[w][4] = a4;
    }
    __syncthreads();
    if (threadIdx.x == 0) {
        double f0 = 0, f1 = 0, f2 = 0, f3 = 0, f4 = 0;
        for (int i = 0; i < 16; ++i) {
            f0 += red[i][0]; f1 += red[i][1]; f2 += red[i][2];
            f3 += red[i][3]; f4 += red[i][4];
        }
        fin[0] = f0; fin[1] = f1; fin[2] = f2; fin[3] = f3; fin[4] = f4;
    }
    __syncthreads();
    if (threadIdx.x >= 64) return;

    int lane = threadIdx.x;
    double SP = fin[0], SPT = fin[1], ST = fin[2], SGT = fin[3];
    long long CNT = (long long)fin[4];

    double vlo = (double)g_band[0], vhi = (double)g_band[1];
    double binw = (vhi - vlo) / NB2;
    long long k2 = k - CNT;

    int base = lane << 6;               // 64 bins per lane (LDS-resident)
    unsigned long long cchunk = 0;
    double wchunk = 0.0;
    for (int j = 0; j < 64; ++j) {
        unsigned h = lh[base + j];
        cchunk += h;
        wchunk += (double)h * (vlo + (base + j + 0.5) * binw);
    }
    unsigned long long cs = cchunk;
    double wsum = wchunk;
    #pragma unroll
    for (int off = 1; off < 64; off <<= 1) {
        unsigned long long cv = __shfl_down(cs, off);
        double wv = __shfl_down(wsum, off);
        if (lane + off < 64) { cs += cv; wsum += wv; }
    }
    unsigned long long total = __shfl(cs, 0);
    double wtotal = __shfl(wsum, 0);

    double I = SPT, U = SP + ST;
    double dice_part = 0.5 * (1.0 - (2.0 * I + 1e-6) / (U + 1e-6));

    if (k2 <= 0) {
        if (lane == 0) out[0] = (float)(SGT / (double)k + dice_part);
        return;
    }
    if ((unsigned long long)k2 > total) {
        if (lane == 0) {
            double sum_top = SGT + wtotal + (double)(k2 - (long long)total) * vlo;
            out[0] = (float)(sum_top / (double)k + dice_part);
        }
        return;
    }
    unsigned long long c = cs - cchunk;
    double wacc = wsum - wchunk;
    for (int j = 63; j >= 0; --j) {
        unsigned h = lh[base + j];
        double val = vlo + (base + j + 0.5) * binw;
        if (c < (unsigned long long)k2 && (unsigned long long)k2 <= c + h) {
            double sum_top = SGT + wacc + (double)((long long)k2 - (long long)c) * val;
            out[0] = (float)(sum_top / (double)k + dice_part);
        }
        c += h;
        wacc += (double)h * val;
    }
}

extern "C" void kernel_launch(void* const* d_in, const int* in_sizes, int n_in,
                              void* d_out, int out_size, void* d_ws, size_t ws_size,
                              hipStream_t stream)
{
    const float* x = (const float*)d_in[0];
    const float* t = (const float*)d_in[1];
    float* out = (float*)d_out;
    int n = in_sizes[0];
    int n4 = n >> 2;
    long long k = (long long)((double)n * 0.2);   // Python int() truncation
    if (k < 1) k = 1;

    // grid sized so ALL blocks are co-resident (spin barrier cannot deadlock):
    // occupancy-API blocks/CU x CU count, computed once (host queries only).
    static int s_grid = 0;
    if (s_grid == 0) {
        int dev = 0; hipGetDevice(&dev);
        int ncu = 0;
        hipDeviceGetAttribute(&ncu, hipDeviceAttributeMultiprocessorCount, dev);
        int nb = 0;
        hipOccupancyMaxActiveBlocksPerMultiprocessor(
            &nb, reinterpret_cast<const void*>(fused_kernel), 256, 0);
        if (ncu <= 0) ncu = 256;
        if (nb < 1) nb = 1;
        long long g = (long long)nb * ncu;
        if (g > 4096) g = 4096;
        s_grid = (int)g;
    }
    int grid = s_grid;
    int per = (n4 + grid - 1) / grid;             // float4 per block
    if (per < 1) per = 1;

    // exact sampled-element count (mirrors device: per-block avail>>4 chunks)
    long long Sf4 = 0;
    for (int b = 0; b < grid; ++b) {
        long long bs = (long long)b * per;
        if (bs >= n4) break;
        long long avail = n4 - bs; if (avail > per) avail = per;
        Sf4 += (avail >> 4);
    }
    long long S = Sf4 * 4;
    long long ks = (S > 0) ? (long long)((double)k * (double)S / (double)n) : 0;
    long long M = 4096;                           // ~6.7 sigma sample-rank margin

    // workspace holds ONLY per-block partials (fully overwritten each call)
    unsigned char* ws = (unsigned char*)d_ws;
    size_t pstride = (((size_t)grid * 4) + 255) & ~(size_t)255;
    float*    q0 = (float*)(ws);
    float*    q1 = (float*)(ws + pstride);
    float*    q2 = (float*)(ws + 2 * pstride);
    float*    q3 = (float*)(ws + 3 * pstride);
    unsigned* qc = (unsigned*)(ws + 4 * pstride);

    fused_kernel<<<grid, 256, 0, stream>>>((const float4*)x, (const float4*)t,
                                           q0, q1, q2, q3, qc, x, t,
                                           n, n4, per, ks, M);
    final_kernel<<<1, 1024, 0, stream>>>(q0, q1, q2, q3, qc, grid, out, k);
}

// Round 11
// 133.110 us; speedup vs baseline: 1.8151x; 1.8151x over previous
//
#include <hip/hip_runtime.h>
#include <math.h>
#include <limits.h>

#define NB1 2048      // coarse bins: (float_bits >> 17) - OFF1  (64 steps/octave)
#define OFF1 6656     // = 104 << 6 : bin 0 at 2^-23; covers up to 2^9
#define NB2 4096      // fine linear histogram bins over the band
#define NREP 4        // replicated global fine-hist copies (blockIdx & 3)
#define GRID_MAIN 2048 // exactly 8 blocks/CU resident: one generation, no tail

// Persistent device state. Invariant: all-zero at kernel_launch entry.
// Zero-initialized at module load; each launch restores zeros before finishing
// (sample_band's last block cleans g_H1/g_done1; final_kernel cleans g_hist2),
// so every call — including rocprof replays — starts from a clean state.
__device__ unsigned g_H1[NB1];
__device__ unsigned g_hist2[NREP * NB2];   // 64 KB, 4 replicated copies
__device__ float    g_band[2];
__device__ unsigned g_done1 = 0;

// loss = max(x,0) - x*t + log1p(exp(-|x|)) >= 0 ; p = sigmoid(x)
__device__ __forceinline__ void elem_f(float x, float t, float& l, float& p) {
    float e = __expf(-fabsf(x));
    l = fmaxf(x, 0.f) - x * t + __logf(1.f + e);
    float r = __builtin_amdgcn_rcpf(1.f + e);
    p = (x >= 0.f) ? r : e * r;
}

// coarse bin for a non-negative loss value (monotonic in value)
__device__ __forceinline__ int coarse_bin(float l) {
    int b = (int)(__float_as_uint(l) >> 17) - OFF1;
    return min(max(b, 0), NB1 - 1);
}

// ---------- k0: 1/16 chunked sample -> coarse bit-histogram ----------
// (R4-proven sampling layout.) 2048 range-limited coarse bins (64/octave):
// 4x cheaper flush/scan than 8192, and a 4x narrower band for main.
// Fused: LAST block performs band selection, self-cleans g_H1.
// NOTE (R9 lesson): do NOT fuse this phase into main — the multi-phase body
// collapses regalloc (VGPR 20) and the coarse-bin LDS atomics bank-conflict
// 64-way when run across the full resident grid (4.4M conflicts measured).
__global__ __launch_bounds__(256) void sample_band_kernel(
    const float4* __restrict__ x4, const float4* __restrict__ t4,
    int n4, long long ks, long long M)
{
    __shared__ unsigned lh[NB1];   // 8 KB
    __shared__ int is_last;
    for (int i = threadIdx.x; i < NB1; i += 256) lh[i] = 0u;
    __syncthreads();

    int nth = gridDim.x * 256;
    int tid = blockIdx.x * 256 + threadIdx.x;
    int S4 = n4 >> 4;              // sampled float4 pairs
    int i0 = tid, i1 = tid + nth;

    float4 xa, ta, xb, tb;
    bool v0 = i0 < S4, v1 = i1 < S4;
    if (v0) {
        int f4 = ((i0 >> 6) << 10) + (i0 & 63);
        xa = x4[f4]; ta = t4[f4];
    }
    if (v1) {
        int f4 = ((i1 >> 6) << 10) + (i1 & 63);
        xb = x4[f4]; tb = t4[f4];
    }
    if (v0) {
        float xs[4] = {xa.x, xa.y, xa.z, xa.w};
        float ts[4] = {ta.x, ta.y, ta.z, ta.w};
        #pragma unroll
        for (int c = 0; c < 4; ++c) {
            float l, p; elem_f(xs[c], ts[c], l, p);
            atomicAdd(&lh[coarse_bin(l)], 1u);
        }
    }
    if (v1) {
        float xs[4] = {xb.x, xb.y, xb.z, xb.w};
        float ts[4] = {tb.x, tb.y, tb.z, tb.w};
        #pragma unroll
        for (int c = 0; c < 4; ++c) {
            float l, p; elem_f(xs[c], ts[c], l, p);
            atomicAdd(&lh[coarse_bin(l)], 1u);
        }
    }
    __syncthreads();
    for (int i = threadIdx.x; i < NB1; i += 256) {
        unsigned c = lh[i];
        if (c) atomicAdd(&g_H1[i], c);
    }
    __syncthreads();

    if (threadIdx.x == 0) {
        __threadfence();           // release
        is_last = (atomicAdd(&g_done1, 1u) == (unsigned)(gridDim.x - 1));
    }
    __syncthreads();
    if (!is_last) return;
    __threadfence();               // acquire

    const uint4* hv = (const uint4*)g_H1;
    uint4* lv = (uint4*)lh;
    for (int i = threadIdx.x; i < NB1 / 4; i += 256) lv[i] = hv[i];
    __syncthreads();
    for (int i = threadIdx.x; i < NB1; i += 256) g_H1[i] = 0u;
    if (threadIdx.x == 0) g_done1 = 0u;

    if (threadIdx.x < 64) {
        int lane = threadIdx.x;
        int base = lane << 5;          // 32 bins per lane
        unsigned long long chunk = 0;
        for (int j = 0; j < 32; ++j) chunk += lh[base + j];
        unsigned long long s = chunk;  // inclusive suffix-scan across lanes
        #pragma unroll
        for (int off = 1; off < 64; off <<= 1) {
            unsigned long long v = __shfl_down(s, off);
            if (lane + off < 64) s += v;
        }
        unsigned long long above = s - chunk;

        int my_bhi = INT_MAX, my_blo = -1;
        unsigned long long c = above;
        for (int j = 31; j >= 0; --j) {
            unsigned h = lh[base + j];
            if ((long long)(c + h) < ks - M) my_bhi = base + j;
            if ((long long)c > ks + M && my_blo < 0) my_blo = base + j;
            c += h;
        }
        #pragma unroll
        for (int off = 32; off; off >>= 1) {
            int a = __shfl_down(my_bhi, off); my_bhi = min(my_bhi, a);
            int b = __shfl_down(my_blo, off); my_blo = max(my_blo, b);
        }
        if (lane == 0) {
            int bhi = (my_bhi == INT_MAX) ? (NB1 - 1) : my_bhi;
            int blo = my_blo;
            float vhi = __uint_as_float((unsigned)(bhi + OFF1) << 17);
            float vlo = (blo < 0) ? 0.f
                                  : __uint_as_float((unsigned)(blo + 1 + OFF1) << 17);
            if (!(vlo < vhi)) vlo = 0.f;
            g_band[0] = vlo;
            g_band[1] = vhi;
        }
    }
}

// ---------- k1: single full pass; per-block partials to private slots ----------
// Grid = 2048 = exactly 8 resident blocks/CU (16.5 KB LDS, low VGPR): ONE
// block generation, no straggler tail. Each block owns a contiguous range of
// n4/2048 float4 (bench: exactly 1152). LDS fine-hist in-loop (DS pipe),
// NREP-replicated atomic flush at block end (R4-proven). Narrow band
// (64-step/octave coarse bins) keeps the masked hist path to ~1-2% of lanes.
__global__ __launch_bounds__(256) void main_kernel(
    const float4* __restrict__ x4, const float4* __restrict__ t4,
    float* __restrict__ q0, float* __restrict__ q1,
    float* __restrict__ q2, float* __restrict__ q3, unsigned* __restrict__ qc,
    const float* __restrict__ xg, const float* __restrict__ tg,
    int n, int n4)
{
    __shared__ unsigned lhist[NB2];    // 16 KB private fine-hist
    for (int i = threadIdx.x; i < NB2; i += 256) lhist[i] = 0u;
    __syncthreads();

    float vlo = g_band[0], vhi = g_band[1];
    float scale = (float)NB2 / (vhi - vlo);

    int per = (n4 + GRID_MAIN - 1) / GRID_MAIN;     // float4 per block
    int base = blockIdx.x * per;
    int end = min(base + per, n4);

    float sp = 0.f, spt = 0.f, st = 0.f, sgt = 0.f;
    unsigned cnt = 0;

    for (int idx = base + threadIdx.x; idx < end; idx += 256) {
        float4 xv = x4[idx], tv = t4[idx];
        float xs[4] = {xv.x, xv.y, xv.z, xv.w};
        float ts[4] = {tv.x, tv.y, tv.z, tv.w};
        #pragma unroll
        for (int c = 0; c < 4; ++c) {
            float l, p;
            elem_f(xs[c], ts[c], l, p);
            sp += p; spt += p * ts[c]; st += ts[c];
            if (l >= vhi) { cnt++; sgt += l; }
            else if (l >= vlo) {
                int b = min((int)((l - vlo) * scale), NB2 - 1);
                atomicAdd(&lhist[b], 1u);
            }
        }
    }

    // scalar tail (n % 4) on block 0
    int tail0 = n4 << 2;
    if (blockIdx.x == 0 && threadIdx.x < (n - tail0)) {
        float x = xg[tail0 + threadIdx.x], t = tg[tail0 + threadIdx.x];
        float l, p;
        elem_f(x, t, l, p);
        sp += p; spt += p * t; st += t;
        if (l >= vhi) { cnt++; sgt += l; }
        else if (l >= vlo) {
            int b = min((int)((l - vlo) * scale), NB2 - 1);
            atomicAdd(&lhist[b], 1u);
        }
    }

    // flush private fine-hist: batched full-wave atomics, NREP-way replicated
    __syncthreads();
    {
        unsigned* dst = &g_hist2[(blockIdx.x & (NREP - 1)) * NB2];
        for (int i = threadIdx.x; i < NB2; i += 256) {
            unsigned c = lhist[i];
            if (c) atomicAdd(&dst[i], c);
        }
    }

    // wave -> block reduce, then ONE private slot write per block
    #pragma unroll
    for (int off = 32; off; off >>= 1) {
        sp  += __shfl_down(sp,  off);
        spt += __shfl_down(spt, off);
        st  += __shfl_down(st,  off);
        sgt += __shfl_down(sgt, off);
        cnt += __shfl_down(cnt, off);
    }
    __shared__ float    rs[4][4];
    __shared__ unsigned rc[4];
    int w = threadIdx.x >> 6;
    if ((threadIdx.x & 63) == 0) {
        rs[w][0] = sp; rs[w][1] = spt; rs[w][2] = st; rs[w][3] = sgt; rc[w] = cnt;
    }
    __syncthreads();
    if (threadIdx.x == 0) {
        float a0 = 0, a1 = 0, a2 = 0, a3 = 0;
        unsigned c = 0;
        #pragma unroll
        for (int i = 0; i < 4; ++i) {
            a0 += rs[i][0]; a1 += rs[i][1]; a2 += rs[i][2]; a3 += rs[i][3]; c += rc[i];
        }
        q0[blockIdx.x] = a0; q1[blockIdx.x] = a1; q2[blockIdx.x] = a2;
        q3[blockIdx.x] = a3; qc[blockIdx.x] = c;
    }
}

// ---------- k2: reduce partials + resolve threshold bin + emit ----------
// Merges the NREP hist copies; self-cleans all of g_hist2 (staged to LDS first).
__global__ __launch_bounds__(1024) void final_kernel(
    const float* __restrict__ q0, const float* __restrict__ q1,
    const float* __restrict__ q2, const float* __restrict__ q3,
    const unsigned* __restrict__ qc, int nblocks,
    float* __restrict__ out, long long k)
{
    __shared__ unsigned lh[NB2];        // 16 KB
    __shared__ double red[16][5];
    __shared__ double fin[5];

    for (int i = threadIdx.x; i < NB2; i += 1024) {
        unsigned s = 0;
        #pragma unroll
        for (int r = 0; r < NREP; ++r) {
            s += g_hist2[r * NB2 + i];
            g_hist2[r * NB2 + i] = 0u;  // self-clean for next call
        }
        lh[i] = s;
    }

    double a0 = 0, a1 = 0, a2 = 0, a3 = 0, a4 = 0;
    for (int i = threadIdx.x; i < nblocks; i += 1024) {
        a0 += (double)q0[i]; a1 += (double)q1[i]; a2 += (double)q2[i];
        a3 += (double)q3[i]; a4 += (double)qc[i];
    }
    #pragma unroll
    for (int off = 32; off; off >>= 1) {
        a0 += __shfl_down(a0, off); a1 += __shfl_down(a1, off);
        a2 += __shfl_down(a2, off); a3 += __shfl_down(a3, off);
        a4 += __shfl_down(a4, off);
    }
    int w = threadIdx.x >> 6;
    if ((threadIdx.x & 63) == 0) {
        red[w][0] = a0; red[w][1] = a1; red[w][2] = a2; red[w][3] = a3; red[w][4] = a4;
    }
    __syncthreads();
    if (threadIdx.x == 0) {
        double f0 = 0, f1 = 0, f2 = 0, f3 = 0, f4 = 0;
        for (int i = 0; i < 16; ++i) {
            f0 += red[i][0]; f1 += red[i][1]; f2 += red[i][2];
            f3 += red[i][3]; f4 += red[i][4];
        }
        fin[0] = f0; fin[1] = f1; fin[2] = f2; fin[3] = f3; fin[4] = f4;
    }
    __syncthreads();
    if (threadIdx.x >= 64) return;

    int lane = threadIdx.x;
    double SP = fin[0], SPT = fin[1], ST = fin[2], SGT = fin[3];
    long long CNT = (long long)fin[4];

    double vlo = (double)g_band[0], vhi = (double)g_band[1];
    double binw = (vhi - vlo) / NB2;
    long long k2 = k - CNT;

    int base = lane << 6;               // 64 bins per lane (LDS-resident)
    unsigned long long cchunk = 0;
    double wchunk = 0.0;
    for (int j = 0; j < 64; ++j) {
        unsigned h = lh[base + j];
        cchunk += h;
        wchunk += (double)h * (vlo + (base + j + 0.5) * binw);
    }
    unsigned long long cs = cchunk;
    double wsum = wchunk;
    #pragma unroll
    for (int off = 1; off < 64; off <<= 1) {
        unsigned long long cv = __shfl_down(cs, off);
        double wv = __shfl_down(wsum, off);
        if (lane + off < 64) { cs += cv; wsum += wv; }
    }
    unsigned long long total = __shfl(cs, 0);
    double wtotal = __shfl(wsum, 0);

    double I = SPT, U = SP + ST;
    double dice_part = 0.5 * (1.0 - (2.0 * I + 1e-6) / (U + 1e-6));

    if (k2 <= 0) {
        if (lane == 0) out[0] = (float)(SGT / (double)k + dice_part);
        return;
    }
    if ((unsigned long long)k2 > total) {
        if (lane == 0) {
            double sum_top = SGT + wtotal + (double)(k2 - (long long)total) * vlo;
            out[0] = (float)(sum_top / (double)k + dice_part);
        }
        return;
    }
    unsigned long long c = cs - cchunk;
    double wacc = wsum - wchunk;
    for (int j = 63; j >= 0; --j) {
        unsigned h = lh[base + j];
        double val = vlo + (base + j + 0.5) * binw;
        if (c < (unsigned long long)k2 && (unsigned long long)k2 <= c + h) {
            double sum_top = SGT + wacc + (double)((long long)k2 - (long long)c) * val;
            out[0] = (float)(sum_top / (double)k + dice_part);
        }
        c += h;
        wacc += (double)h * val;
    }
}

extern "C" void kernel_launch(void* const* d_in, const int* in_sizes, int n_in,
                              void* d_out, int out_size, void* d_ws, size_t ws_size,
                              hipStream_t stream)
{
    const float* x = (const float*)d_in[0];
    const float* t = (const float*)d_in[1];
    float* out = (float*)d_out;
    int n = in_sizes[0];
    int n4 = n >> 2;
    long long k = (long long)((double)n * 0.2);   // Python int() truncation
    if (k < 1) k = 1;

    long long S = (long long)(n4 >> 4) * 4;       // sampled element count (1/16)
    long long ks = (S > 0) ? (long long)((double)k * (double)S / (double)n) : 0;
    long long M = 4096;                           // ~6.7 sigma sample-rank margin

    int S4 = n4 >> 4;                             // sampled float4 pairs
    int sgrid = (S4 + 511) / 512;                 // 2 pairs per thread
    if (sgrid < 1) sgrid = 1;

    // workspace holds ONLY per-block partials (fully overwritten each call)
    unsigned char* ws = (unsigned char*)d_ws;
    size_t pstride = (((size_t)GRID_MAIN * 4) + 255) & ~(size_t)255;
    float*    q0 = (float*)(ws);
    float*    q1 = (float*)(ws + pstride);
    float*    q2 = (float*)(ws + 2 * pstride);
    float*    q3 = (float*)(ws + 3 * pstride);
    unsigned* qc = (unsigned*)(ws + 4 * pstride);

    sample_band_kernel<<<sgrid, 256, 0, stream>>>((const float4*)x, (const float4*)t,
                                                  n4, ks, M);
    main_kernel<<<GRID_MAIN, 256, 0, stream>>>((const float4*)x, (const float4*)t,
                                               q0, q1, q2, q3, qc, x, t, n, n4);
    final_kernel<<<1, 1024, 0, stream>>>(q0, q1, q2, q3, qc, GRID_MAIN, out, k);
}